// Round 13
// baseline (199.090 us; speedup 1.0000x reference)
//
#include <hip/hip_runtime.h>

#define DD 4096
#define NROWS 16384
#define EPS 1e-6f

typedef float fx4 __attribute__((ext_vector_type(4)));
typedef int   ix4 __attribute__((ext_vector_type(4)));

// ws layout:
//   +0      : float gmax
//   +256    : float rowmax[16384]   (normalized per-row max, 64 KB)
//   +1MB    : q8 slots, ROW-PADDED: row r at +r*32KB, 4KB payload
//             region = 512 MB (> L3) -> write-stream heuristic, payload 64 MB
#define Q8_SLOT_DW 8192   // 32KB / 4

// Pass 1: identical to r12 except q8 row stride (32KB slots).
__global__ __launch_bounds__(256) void pass1(
    const float* __restrict__ x, const float* __restrict__ res,
    const float* __restrict__ gamma, unsigned int* __restrict__ q8,
    float* __restrict__ rowmax) {
  const int row = blockIdx.x;
  const int t = threadIdx.x;
  const fx4* x4 = (const fx4*)(x + (size_t)row * DD);
  const fx4* r4 = (const fx4*)(res + (size_t)row * DD);
  const fx4* g4 = (const fx4*)gamma;

  float ss = 0.f, mx = 0.f;
#pragma unroll
  for (int i = 0; i < 4; ++i) {
    const int idx = t + i * 256;  // coalesced
    fx4 xv = x4[idx], rv = r4[idx], gv = g4[idx];
    fx4 y = xv + rv;
    ss += y.x * y.x + y.y * y.y + y.z * y.z + y.w * y.w;
    fx4 p = y * gv;
    mx = fmaxf(mx, fmaxf(fmaxf(fabsf(p.x), fabsf(p.y)),
                         fmaxf(fabsf(p.z), fabsf(p.w))));
  }
#pragma unroll
  for (int off = 32; off > 0; off >>= 1) {
    ss += __shfl_down(ss, off, 64);
    mx = fmaxf(mx, __shfl_down(mx, off, 64));
  }
  __shared__ float s_ss[4], s_mx[4];
  const int wave = t >> 6, lane = t & 63;
  if (lane == 0) { s_ss[wave] = ss; s_mx[wave] = mx; }
  __syncthreads();
  const float tss = s_ss[0] + s_ss[1] + s_ss[2] + s_ss[3];
  const float tmx = fmaxf(fmaxf(s_mx[0], s_mx[1]), fmaxf(s_mx[2], s_mx[3]));
  const float rs = rsqrtf(tss * (1.0f / DD) + EPS);
  if (t == 0) rowmax[row] = tmx * rs;          // normalized row max
  const float inv = tmx > 0.f ? 127.0f / tmx : 0.f;

  unsigned int* qrow = q8 + (size_t)row * Q8_SLOT_DW;  // padded slot
#pragma unroll
  for (int i = 0; i < 4; ++i) {
    const int idx = t + i * 256;
    fx4 xv = x4[idx], rv = r4[idx], gv = g4[idx];  // hot re-read
    fx4 p = (xv + rv) * gv;
    int a = min(max(__float2int_rn(p.x * inv), -127), 127);
    int b = min(max(__float2int_rn(p.y * inv), -127), 127);
    int c = min(max(__float2int_rn(p.z * inv), -127), 127);
    int d = min(max(__float2int_rn(p.w * inv), -127), 127);
    qrow[idx] = (unsigned int)(a & 255) | ((unsigned int)(b & 255) << 8) |
                ((unsigned int)(c & 255) << 16) | ((unsigned int)(d & 255) << 24);
  }
}

__global__ __launch_bounds__(1024) void reduce_gmax(
    const float* __restrict__ rowmax, float* __restrict__ gmax) {
  const int t = threadIdx.x;
  float m = 0.f;
#pragma unroll
  for (int i = 0; i < NROWS / 1024; ++i) m = fmaxf(m, rowmax[t + i * 1024]);
#pragma unroll
  for (int off = 32; off > 0; off >>= 1) m = fmaxf(m, __shfl_down(m, off, 64));
  __shared__ float s[16];
  if ((t & 63) == 0) s[t >> 6] = m;
  __syncthreads();
  if (t == 0) {
    float r = s[0];
#pragma unroll
    for (int i = 1; i < 16; ++i) r = fmaxf(r, s[i]);
    *gmax = r;
  }
}

// Pass 2: out = clamp(rn(q8 * rowmax[row]/gmax)), q8 read from padded slots.
__global__ __launch_bounds__(256) void pass2(
    const unsigned int* __restrict__ q8, const float* __restrict__ rowmax,
    const float* __restrict__ gmax, int* __restrict__ out) {
  const int row = blockIdx.x;
  const float c = rowmax[row] / *gmax;  // <= 1
  const unsigned int* qrow = q8 + (size_t)row * Q8_SLOT_DW;
  ix4* orow = (ix4*)(out + (size_t)row * DD);
#pragma unroll
  for (int i = 0; i < 4; ++i) {
    const int idx = threadIdx.x + i * 256;
    const unsigned int w = qrow[idx];
    ix4 q;
    q.x = min(max(__float2int_rn((float)((int)(w << 24) >> 24) * c), -128), 127);
    q.y = min(max(__float2int_rn((float)((int)(w << 16) >> 24) * c), -128), 127);
    q.z = min(max(__float2int_rn((float)((int)(w << 8) >> 24) * c), -128), 127);
    q.w = min(max(__float2int_rn((float)((int)w >> 24) * c), -128), 127);
    orow[idx] = q;  // 16B/lane coalesced to d_out (fast pattern)
  }
}

// ---- Fallback (ws too small): recompute path, atomic-free ----
__global__ __launch_bounds__(256) void pass1_nb(
    const float* __restrict__ x, const float* __restrict__ res,
    const float* __restrict__ gamma, float* __restrict__ rstd,
    float* __restrict__ rowmax) {
  const int row = blockIdx.x;
  const int t = threadIdx.x;
  const fx4* x4 = (const fx4*)(x + (size_t)row * DD);
  const fx4* r4 = (const fx4*)(res + (size_t)row * DD);
  const fx4* g4 = (const fx4*)gamma;
  float ss = 0.f, mx = 0.f;
#pragma unroll
  for (int i = 0; i < 4; ++i) {
    const int idx = t + i * 256;
    fx4 xv = x4[idx], rv = r4[idx], gv = g4[idx];
    fx4 y = xv + rv;
    ss += y.x * y.x + y.y * y.y + y.z * y.z + y.w * y.w;
    fx4 p = y * gv;
    mx = fmaxf(mx, fmaxf(fmaxf(fabsf(p.x), fabsf(p.y)),
                         fmaxf(fabsf(p.z), fabsf(p.w))));
  }
#pragma unroll
  for (int off = 32; off > 0; off >>= 1) {
    ss += __shfl_down(ss, off, 64);
    mx = fmaxf(mx, __shfl_down(mx, off, 64));
  }
  __shared__ float s_ss[4], s_mx[4];
  const int wave = t >> 6, lane = t & 63;
  if (lane == 0) { s_ss[wave] = ss; s_mx[wave] = mx; }
  __syncthreads();
  if (t == 0) {
    float tss = s_ss[0] + s_ss[1] + s_ss[2] + s_ss[3];
    float tmx = fmaxf(fmaxf(s_mx[0], s_mx[1]), fmaxf(s_mx[2], s_mx[3]));
    float rs = rsqrtf(tss * (1.0f / DD) + EPS);
    rstd[row] = rs;
    rowmax[row] = tmx * rs;
  }
}

__global__ __launch_bounds__(256) void pass2_nb(
    const float* __restrict__ x, const float* __restrict__ res,
    const float* __restrict__ gamma, const float* __restrict__ rstd,
    const float* __restrict__ gmax, int* __restrict__ out) {
  const int row = blockIdx.x;
  const int t = threadIdx.x;
  const float c = rstd[row] * (127.0f / *gmax);
  const fx4* x4 = (const fx4*)(x + (size_t)row * DD);
  const fx4* r4 = (const fx4*)(res + (size_t)row * DD);
  const fx4* g4 = (const fx4*)gamma;
  ix4* o4 = (ix4*)(out + (size_t)row * DD);
#pragma unroll
  for (int i = 0; i < 4; ++i) {
    const int idx = t + i * 256;
    fx4 xv = x4[idx], rv = r4[idx], gv = g4[idx];
    ix4 q;
    q.x = min(max(__float2int_rn((xv.x + rv.x) * gv.x * c), -128), 127);
    q.y = min(max(__float2int_rn((xv.y + rv.y) * gv.y * c), -128), 127);
    q.z = min(max(__float2int_rn((xv.z + rv.z) * gv.z * c), -128), 127);
    q.w = min(max(__float2int_rn((xv.w + rv.w) * gv.w * c), -128), 127);
    o4[idx] = q;
  }
}

extern "C" void kernel_launch(void* const* d_in, const int* in_sizes, int n_in,
                              void* d_out, int out_size, void* d_ws, size_t ws_size,
                              hipStream_t stream) {
  const float* x     = (const float*)d_in[0];
  const float* res   = (const float*)d_in[1];
  const float* gamma = (const float*)d_in[2];
  int* out = (int*)d_out;

  char* ws = (char*)d_ws;
  float* gmax   = (float*)ws;
  float* rowmax = (float*)(ws + 256);
  float* rstd   = (float*)(ws + 256 + 64 * 1024);  // fallback only
  const size_t q8_off = (size_t)1 << 20;
  const size_t need = q8_off + (size_t)NROWS * Q8_SLOT_DW * 4;  // ~513 MB

  if (ws_size >= need) {
    unsigned int* q8 = (unsigned int*)(ws + q8_off);
    pass1<<<NROWS, 256, 0, stream>>>(x, res, gamma, q8, rowmax);
    reduce_gmax<<<1, 1024, 0, stream>>>(rowmax, gmax);
    pass2<<<NROWS, 256, 0, stream>>>(q8, rowmax, gmax, out);
  } else {
    pass1_nb<<<NROWS, 256, 0, stream>>>(x, res, gamma, rstd, rowmax);
    reduce_gmax<<<1, 1024, 0, stream>>>(rowmax, gmax);
    pass2_nb<<<NROWS, 256, 0, stream>>>(x, res, gamma, rstd, gmax, out);
  }
}

// Round 14
// 191.400 us; speedup vs baseline: 1.0402x; 1.0402x over previous
//
#include <hip/hip_runtime.h>

#define DD 4096
#define NROWS 16384
#define EPS 1e-6f

typedef float fx4 __attribute__((ext_vector_type(4)));
typedef int   ix4 __attribute__((ext_vector_type(4)));

// ws layout (tiny now):
//   +0    : float gmax
//   +256  : float rowmax[16384]  (64 KB)
//
// q8 intermediate lives INSIDE d_out: row r's packed int8 occupies dwords
// [4096r, 4096r+1024) — the first quarter of row r's own output span.
// dword (4096r + 4t + i) packs the fx4 at row-local fx4-index (t + 256 i).
// pass2 block r reads only its own slot, then overwrites its span; thread
// t's first store exactly covers the dwords it read (per-thread RAW, no
// cross-thread overlap) -> race-free in-place.

// Pass 1: block-per-row. Read x,res,gamma; p = (x+res)*gamma kept in
// registers across the reduction; after reduction quantize p against the
// row max and store ONE ix4 per thread into d_out's q8 slot.
__global__ __launch_bounds__(256) void pass1(
    const float* __restrict__ x, const float* __restrict__ res,
    const float* __restrict__ gamma, unsigned int* __restrict__ outw,
    float* __restrict__ rowmax) {
  const int row = blockIdx.x;
  const int t = threadIdx.x;
  const fx4* x4 = (const fx4*)(x + (size_t)row * DD);
  const fx4* r4 = (const fx4*)(res + (size_t)row * DD);
  const fx4* g4 = (const fx4*)gamma;

  fx4 p[4];
  float ss = 0.f, mx = 0.f;
#pragma unroll
  for (int i = 0; i < 4; ++i) {
    const int idx = t + i * 256;  // coalesced
    fx4 y = x4[idx] + r4[idx];
    ss += y.x * y.x + y.y * y.y + y.z * y.z + y.w * y.w;
    p[i] = y * g4[idx];
    mx = fmaxf(mx, fmaxf(fmaxf(fabsf(p[i].x), fabsf(p[i].y)),
                         fmaxf(fabsf(p[i].z), fabsf(p[i].w))));
  }
#pragma unroll
  for (int off = 32; off > 0; off >>= 1) {
    ss += __shfl_down(ss, off, 64);
    mx = fmaxf(mx, __shfl_down(mx, off, 64));
  }
  __shared__ float s_ss[4], s_mx[4];
  const int wave = t >> 6, lane = t & 63;
  if (lane == 0) { s_ss[wave] = ss; s_mx[wave] = mx; }
  __syncthreads();
  const float tss = s_ss[0] + s_ss[1] + s_ss[2] + s_ss[3];
  const float tmx = fmaxf(fmaxf(s_mx[0], s_mx[1]), fmaxf(s_mx[2], s_mx[3]));
  const float rs = rsqrtf(tss * (1.0f / DD) + EPS);
  if (t == 0) rowmax[row] = tmx * rs;            // normalized row max
  const float inv = tmx > 0.f ? 127.0f / tmx : 0.f;

  ix4 d;
  int* dp = (int*)&d;
#pragma unroll
  for (int i = 0; i < 4; ++i) {
    int a = min(max(__float2int_rn(p[i].x * inv), -127), 127);
    int b = min(max(__float2int_rn(p[i].y * inv), -127), 127);
    int c = min(max(__float2int_rn(p[i].z * inv), -127), 127);
    int e = min(max(__float2int_rn(p[i].w * inv), -127), 127);
    dp[i] = (a & 255) | ((b & 255) << 8) | ((c & 255) << 16) | ((e & 255) << 24);
  }
  // one coalesced 16B store per thread into row r's q8 slot (in d_out)
  *(ix4*)(outw + (size_t)row * DD + 4 * t) = d;
}

__global__ __launch_bounds__(1024) void reduce_gmax(
    const float* __restrict__ rowmax, float* __restrict__ gmax) {
  const int t = threadIdx.x;
  float m = 0.f;
#pragma unroll
  for (int i = 0; i < NROWS / 1024; ++i) m = fmaxf(m, rowmax[t + i * 1024]);
#pragma unroll
  for (int off = 32; off > 0; off >>= 1) m = fmaxf(m, __shfl_down(m, off, 64));
  __shared__ float s[16];
  if ((t & 63) == 0) s[t >> 6] = m;
  __syncthreads();
  if (t == 0) {
    float r = s[0];
#pragma unroll
    for (int i = 1; i < 16; ++i) r = fmaxf(r, s[i]);
    *gmax = r;
  }
}

// Pass 2: block-per-row, in-place. Read own q8 slot (1 ix4/thread),
// rescale by rowmax[row]/gmax, write the full row (4 ix4/thread).
__global__ __launch_bounds__(256) void pass2(
    unsigned int* __restrict__ outw, const float* __restrict__ rowmax,
    const float* __restrict__ gmax, int* __restrict__ out) {
  const int row = blockIdx.x;
  const int t = threadIdx.x;
  const float c = rowmax[row] / *gmax;  // <= 1
  union { ix4 v; unsigned int w[4]; } u;
  u.v = *(const ix4*)(outw + (size_t)row * DD + 4 * t);  // own slot
  ix4* orow = (ix4*)(out + (size_t)row * DD);
#pragma unroll
  for (int i = 0; i < 4; ++i) {
    const unsigned int w = u.w[i];
    ix4 q;
    q.x = min(max(__float2int_rn((float)((int)(w << 24) >> 24) * c), -128), 127);
    q.y = min(max(__float2int_rn((float)((int)(w << 16) >> 24) * c), -128), 127);
    q.z = min(max(__float2int_rn((float)((int)(w << 8) >> 24) * c), -128), 127);
    q.w = min(max(__float2int_rn((float)((int)w >> 24) * c), -128), 127);
    // i=0 exactly overwrites the dwords this thread just read
    orow[t + i * 256] = q;
  }
}

// ---- Fallback (ws < 1 MB, should not happen): full recompute ----
__global__ __launch_bounds__(256) void pass1_nb(
    const float* __restrict__ x, const float* __restrict__ res,
    const float* __restrict__ gamma, float* __restrict__ rstd,
    float* __restrict__ rowmax) {
  const int row = blockIdx.x;
  const int t = threadIdx.x;
  const fx4* x4 = (const fx4*)(x + (size_t)row * DD);
  const fx4* r4 = (const fx4*)(res + (size_t)row * DD);
  const fx4* g4 = (const fx4*)gamma;
  float ss = 0.f, mx = 0.f;
#pragma unroll
  for (int i = 0; i < 4; ++i) {
    const int idx = t + i * 256;
    fx4 y = x4[idx] + r4[idx];
    ss += y.x * y.x + y.y * y.y + y.z * y.z + y.w * y.w;
    fx4 p = y * g4[idx];
    mx = fmaxf(mx, fmaxf(fmaxf(fabsf(p.x), fabsf(p.y)),
                         fmaxf(fabsf(p.z), fabsf(p.w))));
  }
#pragma unroll
  for (int off = 32; off > 0; off >>= 1) {
    ss += __shfl_down(ss, off, 64);
    mx = fmaxf(mx, __shfl_down(mx, off, 64));
  }
  __shared__ float s_ss[4], s_mx[4];
  const int wave = t >> 6, lane = t & 63;
  if (lane == 0) { s_ss[wave] = ss; s_mx[wave] = mx; }
  __syncthreads();
  if (t == 0) {
    float tss = s_ss[0] + s_ss[1] + s_ss[2] + s_ss[3];
    float tmx = fmaxf(fmaxf(s_mx[0], s_mx[1]), fmaxf(s_mx[2], s_mx[3]));
    float rs = rsqrtf(tss * (1.0f / DD) + EPS);
    rstd[row] = rs;
    rowmax[row] = tmx * rs;
  }
}

__global__ __launch_bounds__(256) void pass2_nb(
    const float* __restrict__ x, const float* __restrict__ res,
    const float* __restrict__ gamma, const float* __restrict__ rstd,
    const float* __restrict__ gmax, int* __restrict__ out) {
  const int row = blockIdx.x;
  const int t = threadIdx.x;
  const float c = rstd[row] * (127.0f / *gmax);
  const fx4* x4 = (const fx4*)(x + (size_t)row * DD);
  const fx4* r4 = (const fx4*)(res + (size_t)row * DD);
  const fx4* g4 = (const fx4*)gamma;
  ix4* o4 = (ix4*)(out + (size_t)row * DD);
#pragma unroll
  for (int i = 0; i < 4; ++i) {
    const int idx = t + i * 256;
    fx4 xv = x4[idx], rv = r4[idx], gv = g4[idx];
    ix4 q;
    q.x = min(max(__float2int_rn((xv.x + rv.x) * gv.x * c), -128), 127);
    q.y = min(max(__float2int_rn((xv.y + rv.y) * gv.y * c), -128), 127);
    q.z = min(max(__float2int_rn((xv.z + rv.z) * gv.z * c), -128), 127);
    q.w = min(max(__float2int_rn((xv.w + rv.w) * gv.w * c), -128), 127);
    o4[idx] = q;
  }
}

extern "C" void kernel_launch(void* const* d_in, const int* in_sizes, int n_in,
                              void* d_out, int out_size, void* d_ws, size_t ws_size,
                              hipStream_t stream) {
  const float* x     = (const float*)d_in[0];
  const float* res   = (const float*)d_in[1];
  const float* gamma = (const float*)d_in[2];
  int* out = (int*)d_out;

  char* ws = (char*)d_ws;
  float* gmax   = (float*)ws;
  float* rowmax = (float*)(ws + 256);
  float* rstd   = (float*)(ws + 256 + 64 * 1024);  // fallback only

  if (ws_size >= (size_t)(2 << 20)) {
    unsigned int* outw = (unsigned int*)d_out;
    pass1<<<NROWS, 256, 0, stream>>>(x, res, gamma, outw, rowmax);
    reduce_gmax<<<1, 1024, 0, stream>>>(rowmax, gmax);
    pass2<<<NROWS, 256, 0, stream>>>(outw, rowmax, gmax, out);
  } else {
    pass1_nb<<<NROWS, 256, 0, stream>>>(x, res, gamma, rstd, rowmax);
    reduce_gmax<<<1, 1024, 0, stream>>>(rowmax, gmax);
    pass2_nb<<<NROWS, 256, 0, stream>>>(x, res, gamma, rstd, gmax, out);
  }
}